// Round 11
// baseline (215.830 us; speedup 1.0000x reference)
//
#include <hip/hip_runtime.h>
#include <hip/hip_bf16.h>
#include <cstdint>

// STFT magnitude via real-packed radix-4 LDS FFT (round 11 = round 8 + occupancy).
// r8 was the best graph total (112.9us). Edits vs r8, all aimed at 2->3 blocks/CU:
//   1. mag staging tile f32 -> bf16 (r9/r10 proved bf16 mags pass: absmax 0.5)
//   2. unpack twiddles (Tun) read from global (coalesced, L1-hot) -- not LDS
//   3. stage twiddles for LOG=2/4/6 hoisted to registers once per kernel
//      (j = lane&3 / lane&15 / lane: u-independent); LOG=8 keeps LDS tst.
// LDS = 32768(z) + 8192(tst) + 8200(mag) = 49160 -> 3 blocks/CU (was 64.5K/2).
// Lesson from r10 (register FFT, shfl FFT4): conflicts were NOT the limit;
// latency hiding is -- do not trade occupancy or add serial twiddle chains.

#define FILT   2048
#define HOP    512
#define CUT    1025
#define NBATCH 32
#define TFR    626
#define NFR    (NBATCH * TFR)      // 20032
#define LSIG   320000
#define LPAD   (LSIG + FILT)       // 322048
#define N2     1024                // complex FFT length

typedef __attribute__((ext_vector_type(8))) short short8;

__device__ __forceinline__ short bf16r(float f) {
  __hip_bfloat16 h = __float2bfloat16(f);
  return __builtin_bit_cast(short, h);
}
__device__ __forceinline__ float bf2f(uint32_t u) {
  return __builtin_bit_cast(float, u << 16);
}

__device__ __forceinline__ short8 pack8(float4 a, float4 b) {
  short8 v;
  v[0] = bf16r(a.x); v[1] = bf16r(a.y); v[2] = bf16r(a.z); v[3] = bf16r(a.w);
  v[4] = bf16r(b.x); v[5] = bf16r(b.y); v[6] = bf16r(b.z); v[7] = bf16r(b.w);
  return v;
}

// -------- stage 1a: reflect-padded signal, f32 -> bf16 [32][LPAD] --------
__global__ void pad_signal(const float* __restrict__ x, short* __restrict__ XP) {
  const int b = blockIdx.y;
  const int i0 = (blockIdx.x * 256 + threadIdx.x) * 8;
  if (i0 >= LPAD) return;
  const float* xb = x + (size_t)b * LSIG;
  const int j0 = i0 - 1024;
  short8 v;
  if (j0 >= 0 && j0 + 8 <= LSIG) {
    float4 a = *(const float4*)(xb + j0);
    float4 c = *(const float4*)(xb + j0 + 4);
    v = pack8(a, c);
  } else {
    #pragma unroll
    for (int e = 0; e < 8; ++e) {
      int j = j0 + e;
      j = j < 0 ? -j : (j >= LSIG ? 2 * LSIG - 2 - j : j);
      v[e] = bf16r(xb[j]);
    }
  }
  *(short8*)&XP[(size_t)b * LPAD + i0] = v;
}

// -------- stage 1b: twiddle + hann tables --------
__global__ void make_tables(float* __restrict__ hann, float2* __restrict__ Tst,
                            float2* __restrict__ Tun) {
  const int i = blockIdx.x * 256 + threadIdx.x;    // 0..2047
  const float PI2 = 6.283185307179586f;
  if (i < 2048) hann[i] = 0.5f - 0.5f * cosf(PI2 * (float)i / 2048.0f);
  if (i < 1024) {
    float s, c;
    sincosf(-PI2 * (float)i / 1024.0f, &s, &c);
    Tst[i] = make_float2(c, s);                    // W_1024^i (forward)
    sincosf(-PI2 * (float)i / 2048.0f, &s, &c);
    Tun[i] = make_float2(c, s);                    // W_2048^i (unpack)
  }
}

__device__ __forceinline__ float2 cmul(float2 a, float2 b) {
  return make_float2(a.x * b.x - a.y * b.y, a.x * b.y + a.y * b.x);
}

__device__ __forceinline__ int SW(int i) { return i ^ ((i >> 4) & 15); }

// radix-4 DIT stage, twiddles from LDS table (LOG=0: none; LOG=8: j=u*64+lane)
template<int LOG>
__device__ __forceinline__ void fft_stage_lds(float2* z, const float2* tw, int lane) {
  constexpr int M4 = 1 << LOG;
  constexpr int STRIDE = 1 << (8 - LOG);
  #pragma unroll
  for (int u = 0; u < 4; ++u) {
    const int bf = u * 64 + lane;
    const int j  = bf & (M4 - 1);
    const int i0 = ((bf >> LOG) << (LOG + 2)) | j;
    const int i1 = i0 + M4, i2 = i0 + 2 * M4, i3 = i0 + 3 * M4;
    const int p0 = SW(i0), p1 = SW(i1), p2 = SW(i2), p3 = SW(i3);
    float2 a = z[p0], b = z[p1], c = z[p2], d = z[p3];
    if (LOG > 0) {
      b = cmul(b, tw[j * STRIDE]);
      c = cmul(c, tw[2 * j * STRIDE]);
      d = cmul(d, tw[3 * j * STRIDE]);
    }
    const float2 t0 = make_float2(a.x + c.x, a.y + c.y);
    const float2 t1 = make_float2(a.x - c.x, a.y - c.y);
    const float2 t2 = make_float2(b.x + d.x, b.y + d.y);
    const float2 t3 = make_float2(b.x - d.x, b.y - d.y);
    z[p0] = make_float2(t0.x + t2.x, t0.y + t2.y);
    z[p1] = make_float2(t1.x + t3.y, t1.y - t3.x);   // t1 - i*t3
    z[p2] = make_float2(t0.x - t2.x, t0.y - t2.y);
    z[p3] = make_float2(t1.x - t3.y, t1.y + t3.x);   // t1 + i*t3
  }
}

// radix-4 DIT stage, twiddles in registers (LOG=2/4/6: j is u-independent)
template<int LOG>
__device__ __forceinline__ void fft_stage_reg(float2* z, float2 w1, float2 w2,
                                              float2 w3, int lane) {
  constexpr int M4 = 1 << LOG;
  const int j = lane & (M4 - 1);                   // == bf & (M4-1) for all u
  #pragma unroll
  for (int u = 0; u < 4; ++u) {
    const int bf = u * 64 + lane;
    const int i0 = ((bf >> LOG) << (LOG + 2)) | j;
    const int i1 = i0 + M4, i2 = i0 + 2 * M4, i3 = i0 + 3 * M4;
    const int p0 = SW(i0), p1 = SW(i1), p2 = SW(i2), p3 = SW(i3);
    float2 a = z[p0], b = z[p1], c = z[p2], d = z[p3];
    b = cmul(b, w1);
    c = cmul(c, w2);
    d = cmul(d, w3);
    const float2 t0 = make_float2(a.x + c.x, a.y + c.y);
    const float2 t1 = make_float2(a.x - c.x, a.y - c.y);
    const float2 t2 = make_float2(b.x + d.x, b.y + d.y);
    const float2 t3 = make_float2(b.x - d.x, b.y - d.y);
    z[p0] = make_float2(t0.x + t2.x, t0.y + t2.y);
    z[p1] = make_float2(t1.x + t3.y, t1.y - t3.x);
    z[p2] = make_float2(t0.x - t2.x, t0.y - t2.y);
    z[p3] = make_float2(t1.x - t3.y, t1.y + t3.x);
  }
}

// -------- stage 2: windowed rFFT magnitude, 1 wave = 1 frame --------
__global__ __launch_bounds__(256)
void stft_fft(const short* __restrict__ XP, const float* __restrict__ hann,
              const float2* __restrict__ Tst, const float2* __restrict__ Tun,
              float* __restrict__ out)
{
  __shared__ float2 zsh[4][1024];    // per-wave z, XOR-swizzled   32768 B
  __shared__ float2 tst[1024];       // stage twiddles (LOG=8)      8192 B
  __shared__ ushort mag[4][1025];    // staged bf16 magnitudes      8200 B

  const int tid = threadIdx.x, wv = tid >> 6, lane = tid & 63;
  #pragma unroll
  for (int u = 0; u < 4; ++u) tst[u * 256 + tid] = Tst[u * 256 + tid];

  // hoisted u-independent stage twiddles (one-time global gathers)
  const int j2 = lane & 3, j4 = lane & 15, j6 = lane;
  const float2 w21 = Tst[j2 * 64], w22 = Tst[2 * j2 * 64], w23 = Tst[3 * j2 * 64];
  const float2 w41 = Tst[j4 * 16], w42 = Tst[2 * j4 * 16], w43 = Tst[3 * j4 * 16];
  const float2 w61 = Tst[j6 * 4],  w62 = Tst[2 * j6 * 4],  w63 = Tst[3 * j6 * 4];
  __syncthreads();

  float2* z = zsh[wv];
  const int bid = blockIdx.x;

  for (int q = 0; q < 4; ++q) {
    const int f = bid * 16 + q * 4 + wv;           // 4 consecutive frames per q
    const int b = f / TFR, t = f - b * TFR;
    const short* base = XP + (size_t)b * LPAD + (size_t)t * HOP;

    // load pair (x[2i], x[2i+1]), window, store digit-reversed (own z: no bar)
    #pragma unroll
    for (int u = 0; u < 16; ++u) {
      const int i = u * 64 + lane;
      const uint32_t pr = *(const uint32_t*)(base + 2 * i);
      const float xe = __builtin_bit_cast(float, pr << 16);
      const float xo = __builtin_bit_cast(float, pr & 0xffff0000u);
      const float2 h = *(const float2*)(hann + 2 * i);
      int r = __brev((unsigned)i) >> 22;               // 10-bit bit-reverse
      r = ((r & 0x155) << 1) | ((r >> 1) & 0x155);     // -> base-4 digit-reverse
      z[SW(r)] = make_float2(xe * h.x, xo * h.y);
    }

    fft_stage_lds<0>(z, tst, lane);
    fft_stage_reg<2>(z, w21, w22, w23, lane);
    fft_stage_reg<4>(z, w41, w42, w43, lane);
    fft_stage_reg<6>(z, w61, w62, w63, lane);
    fft_stage_lds<8>(z, tst, lane);

    // unpack real FFT + magnitude -> bf16 mag[wv][*] (Tun from global, coalesced)
    #pragma unroll
    for (int v = 0; v < 16; ++v) {
      const int k = v * 64 + lane;
      const float2 Zk = z[SW(k)];
      const int km = (N2 - k) & (N2 - 1);
      const float2 Zm = z[SW(km)];
      const float xer = 0.5f * (Zk.x + Zm.x);
      const float xei = 0.5f * (Zk.y - Zm.y);
      const float xor_ = 0.5f * (Zk.y + Zm.y);
      const float xoi = -0.5f * (Zk.x - Zm.x);
      const float2 w = Tun[k];
      const float Xr = xer + w.x * xor_ - w.y * xoi;
      const float Xi = xei + w.x * xoi + w.y * xor_;
      mag[wv][k] = (ushort)bf16r(sqrtf(Xr * Xr + Xi * Xi));
    }
    if (lane == 0) {                                   // Nyquist bin
      const float2 Z0 = z[0];
      mag[wv][N2] = (ushort)bf16r(fabsf(Z0.x - Z0.y));
    }
    __syncthreads();

    // write phase: per bin, 4 consecutive t -> 2x float2 (16B/line-touch)
    const int fq0 = bid * 16 + q * 4;
    const int b0 = fq0 / TFR, t0 = fq0 - b0 * TFR;
    if (t0 + 3 < TFR) {
      for (int kk = tid; kk < 1025; kk += 256) {
        float* p = out + (size_t)b0 * (CUT * TFR) + (size_t)kk * TFR + t0;
        *(float2*)p       = make_float2(bf2f(mag[0][kk]), bf2f(mag[1][kk]));
        *(float2*)(p + 2) = make_float2(bf2f(mag[2][kk]), bf2f(mag[3][kk]));
      }
    } else {                                           // batch-straddling group
      for (int kk = tid; kk < 1025; kk += 256) {
        #pragma unroll
        for (int w = 0; w < 4; ++w) {
          const int ff = fq0 + w;
          const int bb = ff / TFR, tt = ff - bb * TFR;
          out[(size_t)bb * (CUT * TFR) + (size_t)kk * TFR + tt] = bf2f(mag[w][kk]);
        }
      }
    }
    __syncthreads();
  }
}

// -------- fallback: reg-staged 128x128 MFMA GEMM (no ws needed) --------
typedef __attribute__((ext_vector_type(4))) float f32x4;

__global__ __launch_bounds__(256, 2)
void stft_gemm_fb(const float* __restrict__ basis, const float* __restrict__ x,
                  float* __restrict__ out)
{
  __shared__ alignas(16) short sA[2][128][64];
  __shared__ alignas(16) short sB[128][64];

  const int tid  = threadIdx.x;
  const int wave = tid >> 6;
  const int lane = tid & 63;
  const int n0 = blockIdx.x * 128;
  const int m0 = blockIdx.y * 128;

  f32x4 acc_r[4][4], acc_i[4][4];
  #pragma unroll
  for (int i = 0; i < 4; ++i)
    #pragma unroll
    for (int j = 0; j < 4; ++j) { acc_r[i][j] = (f32x4)0.f; acc_i[i][j] = (f32x4)0.f; }

  const int sr = tid >> 1;
  const int sh = (tid & 1) * 32;

  for (int k0 = 0; k0 < FILT; k0 += 64) {
    #pragma unroll
    for (int p = 0; p < 2; ++p) {
      const int k = m0 + sr;
      short8 v[4];
      if (k < CUT) {
        const float* src = basis + (size_t)(p * CUT + k) * FILT + k0 + sh;
        #pragma unroll
        for (int qq = 0; qq < 4; ++qq) {
          float4 a = *(const float4*)(src + qq * 8);
          float4 b = *(const float4*)(src + qq * 8 + 4);
          v[qq] = pack8(a, b);
        }
      } else {
        #pragma unroll
        for (int qq = 0; qq < 4; ++qq) v[qq] = (short8)(short)0;
      }
      #pragma unroll
      for (int qq = 0; qq < 4; ++qq) *(short8*)&sA[p][sr][sh + qq * 8] = v[qq];
    }
    {
      const int f = n0 + sr;
      short8 v[4];
      if (f < NFR) {
        const int b = f / TFR, t = f - b * TFR;
        const float* xb = x + (size_t)b * LSIG;
        const int j0 = t * HOP + k0 + sh - 1024;
        if (j0 >= 0 && j0 + 32 <= LSIG) {
          #pragma unroll
          for (int qq = 0; qq < 4; ++qq) {
            float4 a  = *(const float4*)(xb + j0 + qq * 8);
            float4 b2 = *(const float4*)(xb + j0 + qq * 8 + 4);
            v[qq] = pack8(a, b2);
          }
        } else {
          #pragma unroll
          for (int qq = 0; qq < 4; ++qq)
            #pragma unroll
            for (int e = 0; e < 8; ++e) {
              int j = j0 + qq * 8 + e;
              j = j < 0 ? -j : (j >= LSIG ? 2 * LSIG - 2 - j : j);
              v[qq][e] = bf16r(xb[j]);
            }
        }
      } else {
        #pragma unroll
        for (int qq = 0; qq < 4; ++qq) v[qq] = (short8)(short)0;
      }
      #pragma unroll
      for (int qq = 0; qq < 4; ++qq) *(short8*)&sB[sr][sh + qq * 8] = v[qq];
    }
    __syncthreads();

    const int ra = lane & 15;
    #pragma unroll
    for (int kk = 0; kk < 64; kk += 32) {
      const int col = kk + (lane >> 4) * 8;
      short8 arr[4], aii[4], bfr[4];
      #pragma unroll
      for (int i = 0; i < 4; ++i) {
        const int rm = (wave >> 1) * 64 + i * 16 + ra;
        arr[i] = *(const short8*)&sA[0][rm][col];
        aii[i] = *(const short8*)&sA[1][rm][col];
        const int rn = (wave & 1) * 64 + i * 16 + ra;
        bfr[i] = *(const short8*)&sB[rn][col];
      }
      #pragma unroll
      for (int i = 0; i < 4; ++i)
        #pragma unroll
        for (int j = 0; j < 4; ++j) {
          acc_r[i][j] = __builtin_amdgcn_mfma_f32_16x16x32_bf16(arr[i], bfr[j], acc_r[i][j], 0, 0, 0);
          acc_i[i][j] = __builtin_amdgcn_mfma_f32_16x16x32_bf16(aii[i], bfr[j], acc_i[i][j], 0, 0, 0);
        }
    }
    __syncthreads();
  }

  const int wm0 = m0 + (wave >> 1) * 64;
  const int wn0 = n0 + (wave & 1) * 64;
  const int cl = lane & 15;
  const int rg = (lane >> 4) * 4;
  #pragma unroll
  for (int j = 0; j < 4; ++j) {
    const int f = wn0 + j * 16 + cl;
    if (f >= NFR) continue;
    const int b = f / TFR, t = f - b * TFR;
    float* ob = out + (size_t)b * (CUT * TFR) + t;
    #pragma unroll
    for (int i = 0; i < 4; ++i) {
      #pragma unroll
      for (int r = 0; r < 4; ++r) {
        const int k = wm0 + i * 16 + rg + r;
        if (k < CUT) {
          float re = acc_r[i][j][r], im = acc_i[i][j][r];
          ob[(size_t)k * TFR] = sqrtf(re * re + im * im);
        }
      }
    }
  }
}

extern "C" void kernel_launch(void* const* d_in, const int* in_sizes, int n_in,
                              void* d_out, int out_size, void* d_ws, size_t ws_size,
                              hipStream_t stream) {
  const float* x     = (const float*)d_in[0];
  const float* basis = (const float*)d_in[1];
  float* out = (float*)d_out;

  const size_t sbytes = (size_t)NBATCH * LPAD * sizeof(short);   // 20,611,072
  const size_t hbytes = 2048 * sizeof(float);                    // 8 KB
  const size_t tbytes = 1024 * sizeof(float2);                   // 8 KB each

  if (ws_size >= sbytes + hbytes + 2 * tbytes) {
    short*  XP   = (short*)d_ws;
    float*  hann = (float*)((char*)d_ws + sbytes);
    float2* Tst  = (float2*)((char*)d_ws + sbytes + hbytes);
    float2* Tun  = (float2*)((char*)d_ws + sbytes + hbytes + tbytes);
    pad_signal<<<dim3((LPAD + 2047) / 2048, NBATCH), 256, 0, stream>>>(x, XP);
    make_tables<<<8, 256, 0, stream>>>(hann, Tst, Tun);
    stft_fft<<<NFR / 16, 256, 0, stream>>>(XP, hann, Tst, Tun, out);
  } else {
    stft_gemm_fb<<<dim3(157, 9), 256, 0, stream>>>(basis, x, out);
  }
}

// Round 12
// 115.047 us; speedup vs baseline: 1.8760x; 1.8760x over previous
//
#include <hip/hip_runtime.h>
#include <hip/hip_bf16.h>
#include <cstdint>

// STFT magnitude via real-packed radix-4 LDS FFT (round 12 = r8 core + write fix).
// r8 (112.9us total) is the champion; its measured wastes were 206MB HBM writes
// (16B-dirty 64B lines) and 8 barrier convoys/block. This round:
//   1. buffer ALL 16 frames' magnitudes as bf16 in LDS (33KB; Tun moves to
//      global, coalesced+L1-hot) -> ONE barrier, ONE write phase emitting
//      fully-dirty 64B lines (8x float2, alignment verified: t0 even,
//      kk*TFR*4 % 8 == 0). LDS 73,984B -> still 2 blocks/CU.
//   2. mirror-pair unpack: X[1024-k] = conj(Xe - w*Xo)  (Xe/Xo conj-symmetric,
//      W^(1024-k) = -conj(W^k)) -> bins k and 1024-k from one (Zk,Zm,w) triple;
//      unpack LDS reads and Tun reads halve; k=0 gives Nyquist exactly.
// FFT core (load/scatter/5 stages/tst) is byte-identical to r8. Lessons kept:
// never trade occupancy (r5/r11), no serial twiddle chains (r10/r11).

#define FILT   2048
#define HOP    512
#define CUT    1025
#define NBATCH 32
#define TFR    626
#define NFR    (NBATCH * TFR)      // 20032
#define LSIG   320000
#define LPAD   (LSIG + FILT)       // 322048
#define N2     1024                // complex FFT length

typedef __attribute__((ext_vector_type(8))) short short8;

__device__ __forceinline__ short bf16r(float f) {
  __hip_bfloat16 h = __float2bfloat16(f);
  return __builtin_bit_cast(short, h);
}
__device__ __forceinline__ float bf2f(uint32_t u) {
  return __builtin_bit_cast(float, u << 16);
}

__device__ __forceinline__ short8 pack8(float4 a, float4 b) {
  short8 v;
  v[0] = bf16r(a.x); v[1] = bf16r(a.y); v[2] = bf16r(a.z); v[3] = bf16r(a.w);
  v[4] = bf16r(b.x); v[5] = bf16r(b.y); v[6] = bf16r(b.z); v[7] = bf16r(b.w);
  return v;
}

// -------- stage 1a: reflect-padded signal, f32 -> bf16 [32][LPAD] --------
__global__ void pad_signal(const float* __restrict__ x, short* __restrict__ XP) {
  const int b = blockIdx.y;
  const int i0 = (blockIdx.x * 256 + threadIdx.x) * 8;
  if (i0 >= LPAD) return;
  const float* xb = x + (size_t)b * LSIG;
  const int j0 = i0 - 1024;
  short8 v;
  if (j0 >= 0 && j0 + 8 <= LSIG) {
    float4 a = *(const float4*)(xb + j0);
    float4 c = *(const float4*)(xb + j0 + 4);
    v = pack8(a, c);
  } else {
    #pragma unroll
    for (int e = 0; e < 8; ++e) {
      int j = j0 + e;
      j = j < 0 ? -j : (j >= LSIG ? 2 * LSIG - 2 - j : j);
      v[e] = bf16r(xb[j]);
    }
  }
  *(short8*)&XP[(size_t)b * LPAD + i0] = v;
}

// -------- stage 1b: twiddle + hann tables --------
__global__ void make_tables(float* __restrict__ hann, float2* __restrict__ Tst,
                            float2* __restrict__ Tun) {
  const int i = blockIdx.x * 256 + threadIdx.x;    // 0..2047
  const float PI2 = 6.283185307179586f;
  if (i < 2048) hann[i] = 0.5f - 0.5f * cosf(PI2 * (float)i / 2048.0f);
  if (i < 1024) {
    float s, c;
    sincosf(-PI2 * (float)i / 1024.0f, &s, &c);
    Tst[i] = make_float2(c, s);                    // W_1024^i (forward)
    sincosf(-PI2 * (float)i / 2048.0f, &s, &c);
    Tun[i] = make_float2(c, s);                    // W_2048^i (unpack)
  }
}

__device__ __forceinline__ float2 cmul(float2 a, float2 b) {
  return make_float2(a.x * b.x - a.y * b.y, a.x * b.y + a.y * b.x);
}

__device__ __forceinline__ int SW(int i) { return i ^ ((i >> 4) & 15); }

// radix-4 DIT stage (r8-identical): M4 = 1<<LOG, twiddle stride = 1<<(8-LOG)
template<int LOG>
__device__ __forceinline__ void fft_stage(float2* z, const float2* tw, int lane) {
  constexpr int M4 = 1 << LOG;
  constexpr int STRIDE = 1 << (8 - LOG);
  #pragma unroll
  for (int u = 0; u < 4; ++u) {
    const int bf = u * 64 + lane;                  // butterfly id 0..255
    const int j  = bf & (M4 - 1);
    const int i0 = ((bf >> LOG) << (LOG + 2)) | j;
    const int i1 = i0 + M4, i2 = i0 + 2 * M4, i3 = i0 + 3 * M4;
    const int p0 = SW(i0), p1 = SW(i1), p2 = SW(i2), p3 = SW(i3);
    float2 a = z[p0], b = z[p1], c = z[p2], d = z[p3];
    if (LOG > 0) {
      b = cmul(b, tw[j * STRIDE]);
      c = cmul(c, tw[2 * j * STRIDE]);
      d = cmul(d, tw[3 * j * STRIDE]);
    }
    const float2 t0 = make_float2(a.x + c.x, a.y + c.y);
    const float2 t1 = make_float2(a.x - c.x, a.y - c.y);
    const float2 t2 = make_float2(b.x + d.x, b.y + d.y);
    const float2 t3 = make_float2(b.x - d.x, b.y - d.y);
    z[p0] = make_float2(t0.x + t2.x, t0.y + t2.y);
    z[p1] = make_float2(t1.x + t3.y, t1.y - t3.x);   // t1 - i*t3
    z[p2] = make_float2(t0.x - t2.x, t0.y - t2.y);
    z[p3] = make_float2(t1.x - t3.y, t1.y + t3.x);   // t1 + i*t3
  }
}

// -------- stage 2: windowed rFFT magnitude, 1 wave = 1 frame --------
__global__ __launch_bounds__(256)
void stft_fft(const short* __restrict__ XP, const float* __restrict__ hann,
              const float2* __restrict__ Tst, const float2* __restrict__ Tun,
              float* __restrict__ out)
{
  __shared__ float2 zsh[4][1024];    // per-wave z, XOR-swizzled   32768 B
  __shared__ float2 tst[1024];       // stage twiddles              8192 B
  __shared__ ushort mag[16][1032];   // bf16 mags, 16 frames       33024 B  (73984 total)

  const int tid = threadIdx.x, wv = tid >> 6, lane = tid & 63;
  #pragma unroll
  for (int u = 0; u < 4; ++u) tst[u * 256 + tid] = Tst[u * 256 + tid];
  __syncthreads();                   // tables ready

  float2* z = zsh[wv];
  const int bid = blockIdx.x;

  for (int q = 0; q < 4; ++q) {
    const int f = bid * 16 + q * 4 + wv;
    const int b = f / TFR, t = f - b * TFR;
    const short* base = XP + (size_t)b * LPAD + (size_t)t * HOP;

    // load pair (x[2i], x[2i+1]), window, store digit-reversed (own z: no bar)
    #pragma unroll
    for (int u = 0; u < 16; ++u) {
      const int i = u * 64 + lane;
      const uint32_t pr = *(const uint32_t*)(base + 2 * i);
      const float xe = __builtin_bit_cast(float, pr << 16);
      const float xo = __builtin_bit_cast(float, pr & 0xffff0000u);
      const float2 h = *(const float2*)(hann + 2 * i);
      int r = __brev((unsigned)i) >> 22;               // 10-bit bit-reverse
      r = ((r & 0x155) << 1) | ((r >> 1) & 0x155);     // -> base-4 digit-reverse
      z[SW(r)] = make_float2(xe * h.x, xo * h.y);
    }

    fft_stage<0>(z, tst, lane);
    fft_stage<2>(z, tst, lane);
    fft_stage<4>(z, tst, lane);
    fft_stage<6>(z, tst, lane);
    fft_stage<8>(z, tst, lane);

    // mirror-pair unpack: bins k and 1024-k from one (Zk,Zm,w) triple.
    // X[k] = Xe + w*Xo;  |X[1024-k]| = |Xe - w*Xo|  (conj dropped under |.|)
    ushort* mrow = mag[q * 4 + wv];
    #pragma unroll
    for (int v = 0; v < 8; ++v) {
      const int k = v * 64 + lane;                     // 0..511
      const float2 Zk = z[SW(k)];
      const int km = (N2 - k) & (N2 - 1);
      const float2 Zm = z[SW(km)];
      const float xer = 0.5f * (Zk.x + Zm.x);
      const float xei = 0.5f * (Zk.y - Zm.y);
      const float xor_ = 0.5f * (Zk.y + Zm.y);
      const float xoi = -0.5f * (Zk.x - Zm.x);
      const float2 w = Tun[k];                         // global, coalesced, L1-hot
      const float px = w.x * xor_ - w.y * xoi;         // (w*Xo).re
      const float py = w.x * xoi + w.y * xor_;         // (w*Xo).im
      const float Xr = xer + px, Xi = xei + py;
      const float Yr = xer - px, Yi = xei - py;
      mrow[k]        = (ushort)bf16r(sqrtf(Xr * Xr + Xi * Xi));
      mrow[1024 - k] = (ushort)bf16r(sqrtf(Yr * Yr + Yi * Yi));
    }
    if (lane == 0) {                                   // k=512 self-paired:
      const float2 Zc = z[SW(512)];                    // X = Xe - i*Xo, both real
      mrow[512] = (ushort)bf16r(sqrtf(Zc.x * Zc.x + Zc.y * Zc.y));
    }
  }
  __syncthreads();                   // the ONLY post-prologue barrier

  // single write phase: 16 consecutive frames per bin -> fully-dirty 64B lines
  const int fq0 = bid * 16;
  const int b0 = fq0 / TFR, t0 = fq0 - b0 * TFR;
  if (t0 + 15 < TFR) {
    for (int kk = tid; kk < 1025; kk += 256) {
      float* p = out + (size_t)b0 * (CUT * TFR) + (size_t)kk * TFR + t0;
      #pragma unroll
      for (int w2 = 0; w2 < 8; ++w2)
        *(float2*)(p + 2 * w2) =
            make_float2(bf2f(mag[2 * w2][kk]), bf2f(mag[2 * w2 + 1][kk]));
    }
  } else {                                             // batch-straddling block
    for (int kk = tid; kk < 1025; kk += 256) {
      #pragma unroll
      for (int w2 = 0; w2 < 16; ++w2) {
        const int ff = fq0 + w2;
        const int bb = ff / TFR, tt = ff - bb * TFR;
        out[(size_t)bb * (CUT * TFR) + (size_t)kk * TFR + tt] = bf2f(mag[w2][kk]);
      }
    }
  }
}

// -------- fallback: reg-staged 128x128 MFMA GEMM (no ws needed) --------
typedef __attribute__((ext_vector_type(4))) float f32x4;

__global__ __launch_bounds__(256, 2)
void stft_gemm_fb(const float* __restrict__ basis, const float* __restrict__ x,
                  float* __restrict__ out)
{
  __shared__ alignas(16) short sA[2][128][64];
  __shared__ alignas(16) short sB[128][64];

  const int tid  = threadIdx.x;
  const int wave = tid >> 6;
  const int lane = tid & 63;
  const int n0 = blockIdx.x * 128;
  const int m0 = blockIdx.y * 128;

  f32x4 acc_r[4][4], acc_i[4][4];
  #pragma unroll
  for (int i = 0; i < 4; ++i)
    #pragma unroll
    for (int j = 0; j < 4; ++j) { acc_r[i][j] = (f32x4)0.f; acc_i[i][j] = (f32x4)0.f; }

  const int sr = tid >> 1;
  const int sh = (tid & 1) * 32;

  for (int k0 = 0; k0 < FILT; k0 += 64) {
    #pragma unroll
    for (int p = 0; p < 2; ++p) {
      const int k = m0 + sr;
      short8 v[4];
      if (k < CUT) {
        const float* src = basis + (size_t)(p * CUT + k) * FILT + k0 + sh;
        #pragma unroll
        for (int qq = 0; qq < 4; ++qq) {
          float4 a = *(const float4*)(src + qq * 8);
          float4 b = *(const float4*)(src + qq * 8 + 4);
          v[qq] = pack8(a, b);
        }
      } else {
        #pragma unroll
        for (int qq = 0; qq < 4; ++qq) v[qq] = (short8)(short)0;
      }
      #pragma unroll
      for (int qq = 0; qq < 4; ++qq) *(short8*)&sA[p][sr][sh + qq * 8] = v[qq];
    }
    {
      const int f = n0 + sr;
      short8 v[4];
      if (f < NFR) {
        const int b = f / TFR, t = f - b * TFR;
        const float* xb = x + (size_t)b * LSIG;
        const int j0 = t * HOP + k0 + sh - 1024;
        if (j0 >= 0 && j0 + 32 <= LSIG) {
          #pragma unroll
          for (int qq = 0; qq < 4; ++qq) {
            float4 a  = *(const float4*)(xb + j0 + qq * 8);
            float4 b2 = *(const float4*)(xb + j0 + qq * 8 + 4);
            v[qq] = pack8(a, b2);
          }
        } else {
          #pragma unroll
          for (int qq = 0; qq < 4; ++qq)
            #pragma unroll
            for (int e = 0; e < 8; ++e) {
              int j = j0 + qq * 8 + e;
              j = j < 0 ? -j : (j >= LSIG ? 2 * LSIG - 2 - j : j);
              v[qq][e] = bf16r(xb[j]);
            }
        }
      } else {
        #pragma unroll
        for (int qq = 0; qq < 4; ++qq) v[qq] = (short8)(short)0;
      }
      #pragma unroll
      for (int qq = 0; qq < 4; ++qq) *(short8*)&sB[sr][sh + qq * 8] = v[qq];
    }
    __syncthreads();

    const int ra = lane & 15;
    #pragma unroll
    for (int kk = 0; kk < 64; kk += 32) {
      const int col = kk + (lane >> 4) * 8;
      short8 arr[4], aii[4], bfr[4];
      #pragma unroll
      for (int i = 0; i < 4; ++i) {
        const int rm = (wave >> 1) * 64 + i * 16 + ra;
        arr[i] = *(const short8*)&sA[0][rm][col];
        aii[i] = *(const short8*)&sA[1][rm][col];
        const int rn = (wave & 1) * 64 + i * 16 + ra;
        bfr[i] = *(const short8*)&sB[rn][col];
      }
      #pragma unroll
      for (int i = 0; i < 4; ++i)
        #pragma unroll
        for (int j = 0; j < 4; ++j) {
          acc_r[i][j] = __builtin_amdgcn_mfma_f32_16x16x32_bf16(arr[i], bfr[j], acc_r[i][j], 0, 0, 0);
          acc_i[i][j] = __builtin_amdgcn_mfma_f32_16x16x32_bf16(aii[i], bfr[j], acc_i[i][j], 0, 0, 0);
        }
    }
    __syncthreads();
  }

  const int wm0 = m0 + (wave >> 1) * 64;
  const int wn0 = n0 + (wave & 1) * 64;
  const int cl = lane & 15;
  const int rg = (lane >> 4) * 4;
  #pragma unroll
  for (int j = 0; j < 4; ++j) {
    const int f = wn0 + j * 16 + cl;
    if (f >= NFR) continue;
    const int b = f / TFR, t = f - b * TFR;
    float* ob = out + (size_t)b * (CUT * TFR) + t;
    #pragma unroll
    for (int i = 0; i < 4; ++i) {
      #pragma unroll
      for (int r = 0; r < 4; ++r) {
        const int k = wm0 + i * 16 + rg + r;
        if (k < CUT) {
          float re = acc_r[i][j][r], im = acc_i[i][j][r];
          ob[(size_t)k * TFR] = sqrtf(re * re + im * im);
        }
      }
    }
  }
}

extern "C" void kernel_launch(void* const* d_in, const int* in_sizes, int n_in,
                              void* d_out, int out_size, void* d_ws, size_t ws_size,
                              hipStream_t stream) {
  const float* x     = (const float*)d_in[0];
  const float* basis = (const float*)d_in[1];
  float* out = (float*)d_out;

  const size_t sbytes = (size_t)NBATCH * LPAD * sizeof(short);   // 20,611,072
  const size_t hbytes = 2048 * sizeof(float);                    // 8 KB
  const size_t tbytes = 1024 * sizeof(float2);                   // 8 KB each

  if (ws_size >= sbytes + hbytes + 2 * tbytes) {
    short*  XP   = (short*)d_ws;
    float*  hann = (float*)((char*)d_ws + sbytes);
    float2* Tst  = (float2*)((char*)d_ws + sbytes + hbytes);
    float2* Tun  = (float2*)((char*)d_ws + sbytes + hbytes + tbytes);
    pad_signal<<<dim3((LPAD + 2047) / 2048, NBATCH), 256, 0, stream>>>(x, XP);
    make_tables<<<8, 256, 0, stream>>>(hann, Tst, Tun);
    stft_fft<<<NFR / 16, 256, 0, stream>>>(XP, hann, Tst, Tun, out);
  } else {
    stft_gemm_fb<<<dim3(157, 9), 256, 0, stream>>>(basis, x, out);
  }
}